// Round 3
// baseline (286.311 us; speedup 1.0000x reference)
//
#include <hip/hip_runtime.h>
#include <hip/hip_bf16.h>

typedef unsigned short u16;

#define BDIM 8
#define LDIM 8192
#define KDIM 256      // C
#define DDIM 256      // D
#define MTOT 65536    // B*L
#define NDIM 1536     // 6*D
#define TCH  32       // scan chunk length
#define NCH  256      // chunks per sequence

// Physical column layout of G (per m-row), dir f in {0,1}, base = f*768:
//   [base + 2d + 0] = h-gate col d   [base + 2d + 1] = z-gate col d  (d<256)
//   [base + 512 + d] = s-gate col d
// NOTE: WcatT rows are phi-permuted (j*16+r -> r*4+j within each 64-col
// block) so the gemm epilogue writes 4 contiguous u16 per lane into the
// LDS C-tile. G's physical layout above is UNCHANGED.

typedef float floatx4 __attribute__((ext_vector_type(4)));
typedef short bf16x8 __attribute__((ext_vector_type(8)));

__device__ __forceinline__ u16 f2bf(float f) {
  union { __hip_bfloat16 h; u16 u; } c;
  c.h = __float2bfloat16(f);
  return c.u;
}
__device__ __forceinline__ float bf2f(u16 u) {
  union { unsigned int i; float f; } c;
  c.i = ((unsigned int)u) << 16;
  return c.f;
}
__device__ __forceinline__ float sigmoidf_fast(float x) {
  return __builtin_amdgcn_rcpf(1.0f + __expf(-x));
}
__device__ __forceinline__ void gll16(const u16* g, u16* l) {
  __builtin_amdgcn_global_load_lds((const __attribute__((address_space(1))) void*)g,
                                   (__attribute__((address_space(3))) void*)l, 16, 0, 0);
}

// ---------------------------------------------------------------------------
// Prep: WcatT row n holds the weight column for PHYSICAL G col phi(n), where
// phi permutes within each 64-col block: n = base + j*16 + r  ->  base + r*4 + j.
// ---------------------------------------------------------------------------
__global__ void prep_weights(const float* __restrict__ Wh1, const float* __restrict__ Wz1,
                             const float* __restrict__ Ws1, const float* __restrict__ Wh_1,
                             const float* __restrict__ Wz_1, const float* __restrict__ Ws_1,
                             const float* __restrict__ bh1, const float* __restrict__ bz1,
                             const float* __restrict__ bs1, const float* __restrict__ bh_1,
                             const float* __restrict__ bz_1, const float* __restrict__ bs_1,
                             u16* __restrict__ WcatT, float* __restrict__ bcat) {
  const int n = blockIdx.x;       // WcatT row (GEMM B-row) 0..1535
  const int k = threadIdx.x;      // 0..255
  const int nn = n & 63;
  const int p = (n & ~63) | ((nn & 15) << 2) | (nn >> 4);   // physical col
  const int dir = p / 768, r = p % 768;
  int d; const float* W; const float* bb;
  if (r < 512) {
    d = r >> 1;
    if (r & 1) { W = dir ? Wz_1 : Wz1; bb = dir ? bz_1 : bz1; }
    else       { W = dir ? Wh_1 : Wh1; bb = dir ? bh_1 : bh1; }
  } else {
    d = r - 512;
    W = dir ? Ws_1 : Ws1; bb = dir ? bs_1 : bs1;
  }
  WcatT[(size_t)n * KDIM + k] = f2bf(W[k * DDIM + d]);
  if (k == 0) bcat[p] = bb[d];
}

// ---------------------------------------------------------------------------
// Convert xs fp32 -> bf16
// ---------------------------------------------------------------------------
__global__ void convert_xs(const float* __restrict__ xs, u16* __restrict__ Abf) {
  size_t i = ((size_t)blockIdx.x * 256 + threadIdx.x) * 8;
  const float4* s = (const float4*)(xs + i);
  float4 f0 = s[0], f1 = s[1];
  union { u16 u[8]; uint4 v; } t;
  t.u[0] = f2bf(f0.x); t.u[1] = f2bf(f0.y); t.u[2] = f2bf(f0.z); t.u[3] = f2bf(f0.w);
  t.u[4] = f2bf(f1.x); t.u[5] = f2bf(f1.y); t.u[6] = f2bf(f1.z); t.u[7] = f2bf(f1.w);
  *(uint4*)(Abf + i) = t.v;
}

// ---------------------------------------------------------------------------
// GEMM: 128x128 tile, BK=64, global_load_lds staging, XCD-swizzled grid.
// Epilogue (all blocks): C-tile -> LDS, __syncthreads() (vmcnt already 0
// here -- the implicit drain is FREE, avoiding round-1's regression where
// the barrier sat behind 32KB of in-flight G stores), then coalesced 16B
// G stores from an LDS readback. hz-blocks additionally run the fused
// phaseA chunk-summary scan from the same LDS tile while G stores retire.
// No inline asm, no raw barriers.
// ---------------------------------------------------------------------------
__global__ __launch_bounds__(256) void gemm_kernel(const u16* __restrict__ Abf,
                                                   const u16* __restrict__ WcatT,
                                                   const float* __restrict__ bcat,
                                                   u16* __restrict__ G,
                                                   float* __restrict__ Acc,
                                                   float* __restrict__ Bcc,
                                                   int fuse) {
  __shared__ __align__(16) u16 sm[16384];   // As(16KB) + Bs(16KB); reused as C-tile
  u16* As = sm;
  u16* Bs = sm + 8192;
  const int tid = threadIdx.x;
  const int lane = tid & 63, wave = tid >> 6;
  const int wm = wave >> 1, wn = wave & 1;
  const int q = lane >> 4, r = lane & 15;

  const int xcd = blockIdx.x & 7;
  const int li  = blockIdx.x >> 3;
  const int mt  = xcd * 64 + li / 12;
  const int nt  = li % 12;
  const int m0 = mt * 128, n0 = nt * 128;

  const u16* gA[4]; const u16* gB[4]; u16* lA[4]; u16* lB[4];
#pragma unroll
  for (int j = 0; j < 4; j++) {
    const int bi = wave * 256 + j * 64 + lane;   // LDS 16B-slot idx
    const int row = bi >> 3;
    const int kq = (bi & 7) ^ (row & 7);         // logical k-block for this slot
    gA[j] = Abf   + (size_t)(m0 + row) * KDIM + kq * 8;
    gB[j] = WcatT + (size_t)(n0 + row) * KDIM + kq * 8;
    lA[j] = As + bi * 8;
    lB[j] = Bs + bi * 8;
  }

  floatx4 acc[4][4];
  floatx4 z4 = {0.f, 0.f, 0.f, 0.f};
#pragma unroll
  for (int i = 0; i < 4; i++)
#pragma unroll
    for (int j = 0; j < 4; j++) acc[i][j] = z4;

  for (int k0 = 0; k0 < KDIM; k0 += 64) {
#pragma unroll
    for (int j = 0; j < 4; j++) { gll16(gA[j] + k0, lA[j]); gll16(gB[j] + k0, lB[j]); }
    __syncthreads();
#pragma unroll
    for (int kk = 0; kk < 2; kk++) {
      bf16x8 af[4], bv[4];
#pragma unroll
      for (int i = 0; i < 4; i++) {
        const int row = wm * 64 + i * 16 + r;
        af[i] = *(const bf16x8*)(As + (row * 8 + ((kk * 4 + q) ^ (row & 7))) * 8);
      }
#pragma unroll
      for (int j = 0; j < 4; j++) {
        const int row = wn * 64 + j * 16 + r;
        bv[j] = *(const bf16x8*)(Bs + (row * 8 + ((kk * 4 + q) ^ (row & 7))) * 8);
      }
#pragma unroll
      for (int i = 0; i < 4; i++)
#pragma unroll
        for (int j = 0; j < 4; j++)
          acc[i][j] = __builtin_amdgcn_mfma_f32_16x16x32_bf16(af[i], bv[j], acc[i][j], 0, 0, 0);
    }
    __syncthreads();
  }

  // Epilogue. C/D layout: col = lane&15, row = (lane>>4)*4 + reg  [m89/m91].
  // Lane (r) holds cols {j*16+r}; phi maps them to physical cols p0..p0+3.
  // Stage bias-added bf16 C-tile to LDS only (no global stores yet).
  const int pcol = wn * 64 + (r << 2);
  const float4 bv4 = *(const float4*)(bcat + n0 + pcol);
  const int hz = fuse && ((n0 % 768) < 512);   // block-uniform
#pragma unroll
  for (int i = 0; i < 4; i++) {
#pragma unroll
    for (int reg = 0; reg < 4; reg++) {
      const int lrow = wm * 64 + i * 16 + q * 4 + reg;
      union { u16 u[4]; uint2 v; } t;
      t.u[0] = f2bf(acc[i][0][reg] + bv4.x);
      t.u[1] = f2bf(acc[i][1][reg] + bv4.y);
      t.u[2] = f2bf(acc[i][2][reg] + bv4.z);
      t.u[3] = f2bf(acc[i][3][reg] + bv4.w);
      *(uint2*)(sm + lrow * 128 + pcol) = t.v;
    }
  }

  __syncthreads();   // vmcnt already 0 -> free drain; orders the LDS tile

  // Coalesced G write: 8 passes x 16B/thread, 256B segments per row.
#pragma unroll
  for (int p = 0; p < 8; p++) {
    const int idx = p * 2048 + tid * 8;        // u16 index within tile
    const int row = idx >> 7, col = idx & 127;
    const uint4 v = *(const uint4*)(sm + idx);
    *(uint4*)(G + (size_t)(m0 + row) * NDIM + n0 + col) = v;
  }

  if (hz) {
    // 4 chunks (one per wave) x 64 d (one per lane); 32-step affine summary.
    const int cc = wave;                 // chunk within tile 0..3
    const int dd = lane;                 // d within tile 0..63
    const int dirn = n0 / 768;
    const int dbase = (n0 % 768) >> 1;   // 0,64,128,192
    const int bb = m0 >> 13;             // batch
    const int c0 = (m0 & 8191) >> 5;     // first chunk of tile
    float h = 0.f, P = 1.f;
#pragma unroll 8
    for (int i = 0; i < TCH; ++i) {
      const int tl = dirn ? (TCH - 1 - i) : i;
      const unsigned int hzv = *(const unsigned int*)(sm + (cc * 32 + tl) * 128 + dd * 2);
      const float z = sigmoidf_fast(bf2f((u16)(hzv >> 16)));
      const float a = 1.f - z;
      h = fmaf(a, h, z * bf2f((u16)(hzv & 0xffffu)));
      P *= a;
    }
    const size_t u = (size_t)dirn * 2048 + (size_t)bb * 256 + (size_t)(c0 + cc);
    Acc[u * 256 + dbase + dd] = P;
    Bcc[u * 256 + dbase + dd] = h;
  }
}

// ---------------------------------------------------------------------------
// Scan phase A (FALLBACK ONLY, used when workspace too small to un-alias):
// per-chunk affine summary. 2 waves per unit, 2 d/lane.
// ---------------------------------------------------------------------------
__global__ __launch_bounds__(256) void scan_phaseA(const u16* __restrict__ G,
                                                   float* __restrict__ Acc,
                                                   float* __restrict__ Bcc) {
  const int slot = threadIdx.x >> 6, lane = threadIdx.x & 63;
  const int w = blockIdx.x * 4 + slot;          // 0..8191
  const int u = w >> 1, half = w & 1;           // unit 0..4095
  const int c = u & 255, b = (u >> 8) & 7, dir = u >> 11;
  const int d0 = half * 128 + lane * 2;
  const u16* p0 = G + (size_t)b * LDIM * NDIM + dir * 768 + d0 * 2;
  float h0 = 0.f, h1 = 0.f, P0 = 1.f, P1 = 1.f;
#pragma unroll 4
  for (int i = 0; i < TCH; ++i) {
    const int t = dir ? (c * TCH + (TCH - 1 - i)) : (c * TCH + i);
    uint2 hz = *(const uint2*)(p0 + (size_t)t * NDIM);
    const u16* q = (const u16*)&hz;
    float z0 = sigmoidf_fast(bf2f(q[1]));
    float z1 = sigmoidf_fast(bf2f(q[3]));
    float a0 = 1.f - z0, a1 = 1.f - z1;
    h0 = fmaf(a0, h0, z0 * bf2f(q[0]));
    h1 = fmaf(a1, h1, z1 * bf2f(q[2]));
    P0 *= a0; P1 *= a1;
  }
  float2 v;
  v.x = P0; v.y = P1;
  *(float2*)(Acc + (size_t)u * 256 + d0) = v;
  v.x = h0; v.y = h1;
  *(float2*)(Bcc + (size_t)u * 256 + d0) = v;
}

// ---------------------------------------------------------------------------
// Scan phase B: chain 256 chunk summaries, 8-deep load batching.
// ---------------------------------------------------------------------------
__global__ void scan_phaseB(const float* __restrict__ Acc, const float* __restrict__ Bcc,
                            const float* __restrict__ h01, const float* __restrict__ h0_1,
                            float* __restrict__ Pref) {
  const int d = threadIdx.x, b = blockIdx.x, dir = blockIdx.y;
  float h = dir ? h0_1[d] : h01[d];
  const size_t ubase = ((size_t)dir * BDIM + b) * NCH;
  if (dir == 0) {
    for (int c0 = 0; c0 < NCH; c0 += 8) {
      float a[8], bb[8];
#pragma unroll
      for (int j = 0; j < 8; ++j) {
        size_t idx = (ubase + c0 + j) * DDIM + d;
        a[j] = Acc[idx]; bb[j] = Bcc[idx];
      }
#pragma unroll
      for (int j = 0; j < 8; ++j) {
        Pref[(ubase + c0 + j) * DDIM + d] = h;
        h = fmaf(a[j], h, bb[j]);
      }
    }
  } else {
    for (int c0 = NCH - 1; c0 >= 0; c0 -= 8) {
      float a[8], bb[8];
#pragma unroll
      for (int j = 0; j < 8; ++j) {
        size_t idx = (ubase + c0 - j) * DDIM + d;
        a[j] = Acc[idx]; bb[j] = Bcc[idx];
      }
#pragma unroll
      for (int j = 0; j < 8; ++j) {
        Pref[(ubase + c0 - j) * DDIM + d] = h;
        h = fmaf(a[j], h, bb[j]);
      }
    }
  }
}

// ---------------------------------------------------------------------------
// Scan phase C (fused, concurrent dirs): block = one (b,c) chunk, 512 thr.
// ---------------------------------------------------------------------------
__global__ __launch_bounds__(512) void scan_phaseC(const u16* __restrict__ G,
                                                   const float* __restrict__ Pref,
                                                   float* __restrict__ out) {
  __shared__ float obuf[TCH * 256];   // 32 KB
  const int c = blockIdx.x & 255, b = blockIdx.x >> 8;
  const int wave = threadIdx.x >> 6, lane = threadIdx.x & 63;
  const int dir = wave >> 2;
  const int d0 = (wave & 3) * 64 + lane;
  const int u = dir * 2048 + b * 256 + c;
  float h = Pref[(size_t)u * 256 + d0];
  const u16* ghz = G + (size_t)b * LDIM * NDIM + dir * 768 + d0 * 2;
  const u16* gs  = G + (size_t)b * LDIM * NDIM + dir * 768 + 512 + d0;

  if (dir == 1) {
#pragma unroll
    for (int i = 0; i < TCH; ++i) {
      const int tl = TCH - 1 - i;
      const int t = c * TCH + tl;
      unsigned int hz = *(const unsigned int*)(ghz + (size_t)t * NDIM);
      u16 sv = gs[(size_t)t * NDIM];
      float z = sigmoidf_fast(bf2f((u16)(hz >> 16)));
      h = fmaf(1.f - z, h, z * bf2f((u16)(hz & 0xffff)));
      obuf[tl * 256 + d0] = h * sigmoidf_fast(bf2f(sv));
    }
    __syncthreads();
  } else {
    float ov[TCH];
#pragma unroll
    for (int i = 0; i < TCH; ++i) {
      const int t = c * TCH + i;
      unsigned int hz = *(const unsigned int*)(ghz + (size_t)t * NDIM);
      u16 sv = gs[(size_t)t * NDIM];
      float z = sigmoidf_fast(bf2f((u16)(hz >> 16)));
      h = fmaf(1.f - z, h, z * bf2f((u16)(hz & 0xffff)));
      ov[i] = h * sigmoidf_fast(bf2f(sv));
    }
    __syncthreads();
#pragma unroll
    for (int i = 0; i < TCH; ++i) {
      const int t = c * TCH + i;
      out[((size_t)b * LDIM + t) * DDIM + d0] = ov[i] + obuf[i * 256 + d0];
    }
  }
}

extern "C" void kernel_launch(void* const* d_in, const int* in_sizes, int n_in,
                              void* d_out, int out_size, void* d_ws, size_t ws_size,
                              hipStream_t stream) {
  const float* xs   = (const float*)d_in[0];
  const float* Wh1  = (const float*)d_in[1];
  const float* bh1  = (const float*)d_in[2];
  const float* Wz1  = (const float*)d_in[3];
  const float* bz1  = (const float*)d_in[4];
  const float* Ws1  = (const float*)d_in[5];
  const float* bs1  = (const float*)d_in[6];
  const float* h01  = (const float*)d_in[7];
  const float* Wh_1 = (const float*)d_in[8];
  const float* bh_1 = (const float*)d_in[9];
  const float* Wz_1 = (const float*)d_in[10];
  const float* bz_1 = (const float*)d_in[11];
  const float* Ws_1 = (const float*)d_in[12];
  const float* bs_1 = (const float*)d_in[13];
  const float* h0_1 = (const float*)d_in[14];
  float* out = (float*)d_out;

  char* ws = (char*)d_ws;
  u16* WcatT = (u16*)ws;   ws += (size_t)NDIM * KDIM * 2;   // 0.75 MB
  float* bcat = (float*)ws; ws += (size_t)NDIM * 4;         // 6 KB
  u16* Abf = (u16*)ws;     ws += (size_t)MTOT * KDIM * 2;   // 32 MB
  u16* G = (u16*)ws;       ws += (size_t)MTOT * NDIM * 2;   // 192 MB

  const size_t sumElems = (size_t)2 * BDIM * NCH * DDIM;    // 1M floats = 4 MB
  float* Acc; float* Bcc; float* Pref;
  int fuse;
  if ((size_t)(ws - (char*)d_ws) + 3 * sumElems * 4 <= ws_size) {
    // Un-aliased summaries -> gemm can write them while Abf is still live.
    Acc  = (float*)ws;
    Bcc  = Acc + sumElems;
    Pref = Bcc + sumElems;
    fuse = 1;
  } else {
    // Fallback: alias Abf (dead after gemm), run separate phaseA.
    if ((size_t)(ws - (char*)d_ws) > ws_size) return;
    Acc  = (float*)Abf;
    Bcc  = Acc + sumElems;
    Pref = Bcc + sumElems;
    fuse = 0;
  }

  prep_weights<<<dim3(NDIM), dim3(KDIM), 0, stream>>>(
      Wh1, Wz1, Ws1, Wh_1, Wz_1, Ws_1, bh1, bz1, bs1, bh_1, bz_1, bs_1, WcatT, bcat);
  convert_xs<<<dim3(MTOT * KDIM / (256 * 8)), dim3(256), 0, stream>>>(xs, Abf);
  gemm_kernel<<<dim3(6144), dim3(256), 0, stream>>>(Abf, WcatT, bcat, G, Acc, Bcc, fuse);
  if (!fuse)
    scan_phaseA<<<dim3(2048), dim3(256), 0, stream>>>(G, Acc, Bcc);
  scan_phaseB<<<dim3(BDIM, 2), dim3(DDIM), 0, stream>>>(Acc, Bcc, h01, h0_1, Pref);
  scan_phaseC<<<dim3(2048), dim3(512), 0, stream>>>(G, Pref, out);
}

// Round 4
// 273.656 us; speedup vs baseline: 1.0462x; 1.0462x over previous
//
#include <hip/hip_runtime.h>
#include <hip/hip_bf16.h>

typedef unsigned short u16;

#define BDIM 8
#define LDIM 8192
#define KDIM 256      // C
#define DDIM 256      // D
#define MTOT 65536    // B*L
#define NDIM 1536     // 6*D
#define TCH  32       // scan chunk length
#define NCH  256      // chunks per sequence

// Physical column layout of G (per m-row), dir f in {0,1}, base = f*768:
//   [base + 2d + 0] = h-gate col d   [base + 2d + 1] = z-gate col d  (d<256)
//   [base + 512 + d] = s-gate col d
// NOTE: WcatT rows are phi-permuted (j*16+r -> r*4+j within each 64-col
// block) so the gemm epilogue writes 4 contiguous u16 per lane. G's
// physical layout above is UNCHANGED.

typedef float floatx4 __attribute__((ext_vector_type(4)));
typedef short bf16x8 __attribute__((ext_vector_type(8)));

__device__ __forceinline__ u16 f2bf(float f) {
  union { __hip_bfloat16 h; u16 u; } c;
  c.h = __float2bfloat16(f);
  return c.u;
}
__device__ __forceinline__ float bf2f(u16 u) {
  union { unsigned int i; float f; } c;
  c.i = ((unsigned int)u) << 16;
  return c.f;
}
__device__ __forceinline__ float sigmoidf_fast(float x) {
  return __builtin_amdgcn_rcpf(1.0f + __expf(-x));
}
__device__ __forceinline__ void gll16(const u16* g, u16* l) {
  __builtin_amdgcn_global_load_lds((const __attribute__((address_space(1))) void*)g,
                                   (__attribute__((address_space(3))) void*)l, 16, 0, 0);
}

// ---------------------------------------------------------------------------
// Prep: WcatT row n holds the weight column for PHYSICAL G col phi(n), where
// phi permutes within each 64-col block: n = base + j*16 + r  ->  base + r*4 + j.
// ---------------------------------------------------------------------------
__global__ void prep_weights(const float* __restrict__ Wh1, const float* __restrict__ Wz1,
                             const float* __restrict__ Ws1, const float* __restrict__ Wh_1,
                             const float* __restrict__ Wz_1, const float* __restrict__ Ws_1,
                             const float* __restrict__ bh1, const float* __restrict__ bz1,
                             const float* __restrict__ bs1, const float* __restrict__ bh_1,
                             const float* __restrict__ bz_1, const float* __restrict__ bs_1,
                             u16* __restrict__ WcatT, float* __restrict__ bcat) {
  const int n = blockIdx.x;       // WcatT row (GEMM B-row) 0..1535
  const int k = threadIdx.x;      // 0..255
  const int nn = n & 63;
  const int p = (n & ~63) | ((nn & 15) << 2) | (nn >> 4);   // physical col
  const int dir = p / 768, r = p % 768;
  int d; const float* W; const float* bb;
  if (r < 512) {
    d = r >> 1;
    if (r & 1) { W = dir ? Wz_1 : Wz1; bb = dir ? bz_1 : bz1; }
    else       { W = dir ? Wh_1 : Wh1; bb = dir ? bh_1 : bh1; }
  } else {
    d = r - 512;
    W = dir ? Ws_1 : Ws1; bb = dir ? bs_1 : bs1;
  }
  WcatT[(size_t)n * KDIM + k] = f2bf(W[k * DDIM + d]);
  if (k == 0) bcat[p] = bb[d];
}

// ---------------------------------------------------------------------------
// Convert xs fp32 -> bf16
// ---------------------------------------------------------------------------
__global__ void convert_xs(const float* __restrict__ xs, u16* __restrict__ Abf) {
  size_t i = ((size_t)blockIdx.x * 256 + threadIdx.x) * 8;
  const float4* s = (const float4*)(xs + i);
  float4 f0 = s[0], f1 = s[1];
  union { u16 u[8]; uint4 v; } t;
  t.u[0] = f2bf(f0.x); t.u[1] = f2bf(f0.y); t.u[2] = f2bf(f0.z); t.u[3] = f2bf(f0.w);
  t.u[4] = f2bf(f1.x); t.u[5] = f2bf(f1.y); t.u[6] = f2bf(f1.z); t.u[7] = f2bf(f1.w);
  *(uint4*)(Abf + i) = t.v;
}

// ---------------------------------------------------------------------------
// GEMM: 128x128 tile, BK=64, global_load_lds staging, XCD-swizzled grid.
// Epilogue: hz-blocks stage C-tile to LDS, free-drain __syncthreads (vmcnt
// already 0), coalesced 16B G stores from LDS readback, then fused phaseA
// chunk-summary scan. s-gate blocks (no scan needed) store directly from
// registers with no extra barrier.
// ---------------------------------------------------------------------------
__global__ __launch_bounds__(256) void gemm_kernel(const u16* __restrict__ Abf,
                                                   const u16* __restrict__ WcatT,
                                                   const float* __restrict__ bcat,
                                                   u16* __restrict__ G,
                                                   float* __restrict__ Acc,
                                                   float* __restrict__ Bcc,
                                                   int fuse) {
  __shared__ __align__(16) u16 sm[16384];   // As(16KB) + Bs(16KB); reused as C-tile
  u16* As = sm;
  u16* Bs = sm + 8192;
  const int tid = threadIdx.x;
  const int lane = tid & 63, wave = tid >> 6;
  const int wm = wave >> 1, wn = wave & 1;
  const int q = lane >> 4, r = lane & 15;

  const int xcd = blockIdx.x & 7;
  const int li  = blockIdx.x >> 3;
  const int mt  = xcd * 64 + li / 12;
  const int nt  = li % 12;
  const int m0 = mt * 128, n0 = nt * 128;

  const u16* gA[4]; const u16* gB[4]; u16* lA[4]; u16* lB[4];
#pragma unroll
  for (int j = 0; j < 4; j++) {
    const int bi = wave * 256 + j * 64 + lane;   // LDS 16B-slot idx
    const int row = bi >> 3;
    const int kq = (bi & 7) ^ (row & 7);         // logical k-block for this slot
    gA[j] = Abf   + (size_t)(m0 + row) * KDIM + kq * 8;
    gB[j] = WcatT + (size_t)(n0 + row) * KDIM + kq * 8;
    lA[j] = As + bi * 8;
    lB[j] = Bs + bi * 8;
  }

  floatx4 acc[4][4];
  floatx4 z4 = {0.f, 0.f, 0.f, 0.f};
#pragma unroll
  for (int i = 0; i < 4; i++)
#pragma unroll
    for (int j = 0; j < 4; j++) acc[i][j] = z4;

  for (int k0 = 0; k0 < KDIM; k0 += 64) {
#pragma unroll
    for (int j = 0; j < 4; j++) { gll16(gA[j] + k0, lA[j]); gll16(gB[j] + k0, lB[j]); }
    __syncthreads();
#pragma unroll
    for (int kk = 0; kk < 2; kk++) {
      bf16x8 af[4], bv[4];
#pragma unroll
      for (int i = 0; i < 4; i++) {
        const int row = wm * 64 + i * 16 + r;
        af[i] = *(const bf16x8*)(As + (row * 8 + ((kk * 4 + q) ^ (row & 7))) * 8);
      }
#pragma unroll
      for (int j = 0; j < 4; j++) {
        const int row = wn * 64 + j * 16 + r;
        bv[j] = *(const bf16x8*)(Bs + (row * 8 + ((kk * 4 + q) ^ (row & 7))) * 8);
      }
#pragma unroll
      for (int i = 0; i < 4; i++)
#pragma unroll
        for (int j = 0; j < 4; j++)
          acc[i][j] = __builtin_amdgcn_mfma_f32_16x16x32_bf16(af[i], bv[j], acc[i][j], 0, 0, 0);
    }
    __syncthreads();
  }

  // Epilogue. C/D layout: col = lane&15, row = (lane>>4)*4 + reg  [m89/m91].
  // Lane (r) holds cols {j*16+r}; phi maps them to physical cols p0..p0+3.
  const int pcol = wn * 64 + (r << 2);
  const float4 bv4 = *(const float4*)(bcat + n0 + pcol);
  const int hz = fuse && ((n0 % 768) < 512);   // block-uniform

  if (hz) {
    // Stage bias-added bf16 C-tile to LDS (no global stores yet).
#pragma unroll
    for (int i = 0; i < 4; i++) {
#pragma unroll
      for (int reg = 0; reg < 4; reg++) {
        const int lrow = wm * 64 + i * 16 + q * 4 + reg;
        union { u16 u[4]; uint2 v; } t;
        t.u[0] = f2bf(acc[i][0][reg] + bv4.x);
        t.u[1] = f2bf(acc[i][1][reg] + bv4.y);
        t.u[2] = f2bf(acc[i][2][reg] + bv4.z);
        t.u[3] = f2bf(acc[i][3][reg] + bv4.w);
        *(uint2*)(sm + lrow * 128 + pcol) = t.v;
      }
    }

    __syncthreads();   // vmcnt already 0 -> free drain; orders the LDS tile

    // Coalesced G write: 8 passes x 16B/thread, 256B segments per row.
#pragma unroll
    for (int p = 0; p < 8; p++) {
      const int idx = p * 2048 + tid * 8;        // u16 index within tile
      const int row = idx >> 7, col = idx & 127;
      const uint4 v = *(const uint4*)(sm + idx);
      *(uint4*)(G + (size_t)(m0 + row) * NDIM + n0 + col) = v;
    }

    // 4 chunks (one per wave) x 64 d (one per lane); 32-step affine summary.
    const int cc = wave;                 // chunk within tile 0..3
    const int dd = lane;                 // d within tile 0..63
    const int dirn = n0 / 768;
    const int dbase = (n0 % 768) >> 1;   // 0,64,128,192
    const int bb = m0 >> 13;             // batch
    const int c0 = (m0 & 8191) >> 5;     // first chunk of tile
    float h = 0.f, P = 1.f;
#pragma unroll 8
    for (int i = 0; i < TCH; ++i) {
      const int tl = dirn ? (TCH - 1 - i) : i;
      const unsigned int hzv = *(const unsigned int*)(sm + (cc * 32 + tl) * 128 + dd * 2);
      const float z = sigmoidf_fast(bf2f((u16)(hzv >> 16)));
      const float a = 1.f - z;
      h = fmaf(a, h, z * bf2f((u16)(hzv & 0xffffu)));
      P *= a;
    }
    const size_t u = (size_t)dirn * 2048 + (size_t)bb * 256 + (size_t)(c0 + cc);
    Acc[u * 256 + dbase + dd] = P;
    Bcc[u * 256 + dbase + dd] = h;
  } else {
    // s-gate block (or fallback): direct 8B stores from registers.
#pragma unroll
    for (int i = 0; i < 4; i++) {
#pragma unroll
      for (int reg = 0; reg < 4; reg++) {
        const int lrow = wm * 64 + i * 16 + q * 4 + reg;
        union { u16 u[4]; uint2 v; } t;
        t.u[0] = f2bf(acc[i][0][reg] + bv4.x);
        t.u[1] = f2bf(acc[i][1][reg] + bv4.y);
        t.u[2] = f2bf(acc[i][2][reg] + bv4.z);
        t.u[3] = f2bf(acc[i][3][reg] + bv4.w);
        *(uint2*)(G + (size_t)(m0 + lrow) * NDIM + n0 + pcol) = t.v;
      }
    }
  }
}

// ---------------------------------------------------------------------------
// Scan phase A (FALLBACK ONLY, used when workspace too small to un-alias):
// per-chunk affine summary. 2 waves per unit, 2 d/lane.
// ---------------------------------------------------------------------------
__global__ __launch_bounds__(256) void scan_phaseA(const u16* __restrict__ G,
                                                   float* __restrict__ Acc,
                                                   float* __restrict__ Bcc) {
  const int slot = threadIdx.x >> 6, lane = threadIdx.x & 63;
  const int w = blockIdx.x * 4 + slot;          // 0..8191
  const int u = w >> 1, half = w & 1;           // unit 0..4095
  const int c = u & 255, b = (u >> 8) & 7, dir = u >> 11;
  const int d0 = half * 128 + lane * 2;
  const u16* p0 = G + (size_t)b * LDIM * NDIM + dir * 768 + d0 * 2;
  float h0 = 0.f, h1 = 0.f, P0 = 1.f, P1 = 1.f;
#pragma unroll 4
  for (int i = 0; i < TCH; ++i) {
    const int t = dir ? (c * TCH + (TCH - 1 - i)) : (c * TCH + i);
    uint2 hz = *(const uint2*)(p0 + (size_t)t * NDIM);
    const u16* q = (const u16*)&hz;
    float z0 = sigmoidf_fast(bf2f(q[1]));
    float z1 = sigmoidf_fast(bf2f(q[3]));
    float a0 = 1.f - z0, a1 = 1.f - z1;
    h0 = fmaf(a0, h0, z0 * bf2f(q[0]));
    h1 = fmaf(a1, h1, z1 * bf2f(q[2]));
    P0 *= a0; P1 *= a1;
  }
  float2 v;
  v.x = P0; v.y = P1;
  *(float2*)(Acc + (size_t)u * 256 + d0) = v;
  v.x = h0; v.y = h1;
  *(float2*)(Bcc + (size_t)u * 256 + d0) = v;
}

// ---------------------------------------------------------------------------
// Scan phase B: chain 256 chunk summaries, 16-deep load batching
// (latency-bound: 16 blocks only; halving batch count halves stall time).
// ---------------------------------------------------------------------------
__global__ void scan_phaseB(const float* __restrict__ Acc, const float* __restrict__ Bcc,
                            const float* __restrict__ h01, const float* __restrict__ h0_1,
                            float* __restrict__ Pref) {
  const int d = threadIdx.x, b = blockIdx.x, dir = blockIdx.y;
  float h = dir ? h0_1[d] : h01[d];
  const size_t ubase = ((size_t)dir * BDIM + b) * NCH;
  if (dir == 0) {
    for (int c0 = 0; c0 < NCH; c0 += 16) {
      float a[16], bb[16];
#pragma unroll
      for (int j = 0; j < 16; ++j) {
        size_t idx = (ubase + c0 + j) * DDIM + d;
        a[j] = Acc[idx]; bb[j] = Bcc[idx];
      }
#pragma unroll
      for (int j = 0; j < 16; ++j) {
        Pref[(ubase + c0 + j) * DDIM + d] = h;
        h = fmaf(a[j], h, bb[j]);
      }
    }
  } else {
    for (int c0 = NCH - 1; c0 >= 0; c0 -= 16) {
      float a[16], bb[16];
#pragma unroll
      for (int j = 0; j < 16; ++j) {
        size_t idx = (ubase + c0 - j) * DDIM + d;
        a[j] = Acc[idx]; bb[j] = Bcc[idx];
      }
#pragma unroll
      for (int j = 0; j < 16; ++j) {
        Pref[(ubase + c0 - j) * DDIM + d] = h;
        h = fmaf(a[j], h, bb[j]);
      }
    }
  }
}

// ---------------------------------------------------------------------------
// Scan phase C: block = one (b,c) chunk, 256 thr, 2 d/lane, both dirs
// concurrent. Staggered 2-phase LDS exchange: phase 1, fwd fills obuf rows
// 0..15 while bwd fills rows 31..16 (disjoint); barrier; phase 2, each side
// continues its chain, reads the OTHER side's obuf row, adds, stores out.
// No per-thread output arrays, no idle tail, vmem instr count halved
// (uint2 h/z + uint s loads).
// ---------------------------------------------------------------------------
__global__ __launch_bounds__(256) void scan_phaseC(const u16* __restrict__ G,
                                                   const float* __restrict__ Pref,
                                                   float* __restrict__ out) {
  __shared__ float obuf[TCH * 256];   // 32 KB
  const int c = blockIdx.x & 255, b = blockIdx.x >> 8;
  const int dir = threadIdx.x >> 7;                       // waves 0-1 fwd, 2-3 bwd
  const int ld  = threadIdx.x & 127;                      // 0..127 within dir
  const int d0 = ld * 2;
  const int u = dir * 2048 + b * 256 + c;
  const float2 h2 = *(const float2*)(Pref + (size_t)u * 256 + d0);
  float h0 = h2.x, h1 = h2.y;
  const u16* ghz = G + (size_t)b * LDIM * NDIM + dir * 768 + d0 * 2;
  const u16* gs  = G + (size_t)b * LDIM * NDIM + dir * 768 + 512 + d0;

  // Phase 1: fwd does tl=0..15, bwd does tl=31..16 (disjoint obuf rows).
#pragma unroll
  for (int i = 0; i < 16; ++i) {
    const int tl = dir ? (TCH - 1 - i) : i;
    const int t = c * TCH + tl;
    const uint2 hz4 = *(const uint2*)(ghz + (size_t)t * NDIM);
    const unsigned int s2 = *(const unsigned int*)(gs + (size_t)t * NDIM);
    const float z0 = sigmoidf_fast(bf2f((u16)(hz4.x >> 16)));
    const float z1 = sigmoidf_fast(bf2f((u16)(hz4.y >> 16)));
    h0 = fmaf(1.f - z0, h0, z0 * bf2f((u16)(hz4.x & 0xffffu)));
    h1 = fmaf(1.f - z1, h1, z1 * bf2f((u16)(hz4.y & 0xffffu)));
    float2 o;
    o.x = h0 * sigmoidf_fast(bf2f((u16)(s2 & 0xffffu)));
    o.y = h1 * sigmoidf_fast(bf2f((u16)(s2 >> 16)));
    *(float2*)(obuf + tl * 256 + d0) = o;
  }

  __syncthreads();

  // Phase 2: fwd does tl=16..31, bwd does tl=15..0; merge with other dir.
#pragma unroll
  for (int i = 16; i < 32; ++i) {
    const int tl = dir ? (TCH - 1 - i) : i;
    const int t = c * TCH + tl;
    const uint2 hz4 = *(const uint2*)(ghz + (size_t)t * NDIM);
    const unsigned int s2 = *(const unsigned int*)(gs + (size_t)t * NDIM);
    const float z0 = sigmoidf_fast(bf2f((u16)(hz4.x >> 16)));
    const float z1 = sigmoidf_fast(bf2f((u16)(hz4.y >> 16)));
    h0 = fmaf(1.f - z0, h0, z0 * bf2f((u16)(hz4.x & 0xffffu)));
    h1 = fmaf(1.f - z1, h1, z1 * bf2f((u16)(hz4.y & 0xffffu)));
    const float o0 = h0 * sigmoidf_fast(bf2f((u16)(s2 & 0xffffu)));
    const float o1 = h1 * sigmoidf_fast(bf2f((u16)(s2 >> 16)));
    const float2 other = *(const float2*)(obuf + tl * 256 + d0);
    float2 res;
    res.x = o0 + other.x;
    res.y = o1 + other.y;
    *(float2*)(out + ((size_t)b * LDIM + t) * DDIM + d0) = res;
  }
}

extern "C" void kernel_launch(void* const* d_in, const int* in_sizes, int n_in,
                              void* d_out, int out_size, void* d_ws, size_t ws_size,
                              hipStream_t stream) {
  const float* xs   = (const float*)d_in[0];
  const float* Wh1  = (const float*)d_in[1];
  const float* bh1  = (const float*)d_in[2];
  const float* Wz1  = (const float*)d_in[3];
  const float* bz1  = (const float*)d_in[4];
  const float* Ws1  = (const float*)d_in[5];
  const float* bs1  = (const float*)d_in[6];
  const float* h01  = (const float*)d_in[7];
  const float* Wh_1 = (const float*)d_in[8];
  const float* bh_1 = (const float*)d_in[9];
  const float* Wz_1 = (const float*)d_in[10];
  const float* bz_1 = (const float*)d_in[11];
  const float* Ws_1 = (const float*)d_in[12];
  const float* bs_1 = (const float*)d_in[13];
  const float* h0_1 = (const float*)d_in[14];
  float* out = (float*)d_out;

  char* ws = (char*)d_ws;
  u16* WcatT = (u16*)ws;   ws += (size_t)NDIM * KDIM * 2;   // 0.75 MB
  float* bcat = (float*)ws; ws += (size_t)NDIM * 4;         // 6 KB
  u16* Abf = (u16*)ws;     ws += (size_t)MTOT * KDIM * 2;   // 32 MB
  u16* G = (u16*)ws;       ws += (size_t)MTOT * NDIM * 2;   // 192 MB

  const size_t sumElems = (size_t)2 * BDIM * NCH * DDIM;    // 1M floats = 4 MB
  float* Acc; float* Bcc; float* Pref;
  int fuse;
  if ((size_t)(ws - (char*)d_ws) + 3 * sumElems * 4 <= ws_size) {
    // Un-aliased summaries -> gemm can write them while Abf is still live.
    Acc  = (float*)ws;
    Bcc  = Acc + sumElems;
    Pref = Bcc + sumElems;
    fuse = 1;
  } else {
    // Fallback: alias Abf (dead after gemm), run separate phaseA.
    if ((size_t)(ws - (char*)d_ws) > ws_size) return;
    Acc  = (float*)Abf;
    Bcc  = Acc + sumElems;
    Pref = Bcc + sumElems;
    fuse = 0;
  }

  prep_weights<<<dim3(NDIM), dim3(KDIM), 0, stream>>>(
      Wh1, Wz1, Ws1, Wh_1, Wz_1, Ws_1, bh1, bz1, bs1, bh_1, bz_1, bs_1, WcatT, bcat);
  convert_xs<<<dim3(MTOT * KDIM / (256 * 8)), dim3(256), 0, stream>>>(xs, Abf);
  gemm_kernel<<<dim3(6144), dim3(256), 0, stream>>>(Abf, WcatT, bcat, G, Acc, Bcc, fuse);
  if (!fuse)
    scan_phaseA<<<dim3(2048), dim3(256), 0, stream>>>(G, Acc, Bcc);
  scan_phaseB<<<dim3(BDIM, 2), dim3(DDIM), 0, stream>>>(Acc, Bcc, h01, h0_1, Pref);
  scan_phaseC<<<dim3(2048), dim3(256), 0, stream>>>(G, Pref, out);
}